// Round 10
// baseline (325.715 us; speedup 1.0000x reference)
//
#include <hip/hip_runtime.h>
#include <hip/hip_cooperative_groups.h>
#include <math.h>

namespace cg = cooperative_groups;

#define BB 8192
#define DD 2048
#define BN_EPS 1e-5f

// ---------------- cooperative fused path ----------------
#define NBLK 512
#define NTHR 256
#define RPB  16   // rows per block   (NBLK * RPB == BB)
#define CPT  8    // cols per thread  (NTHR * CPT == DD)
#define NWV  (NTHR / 64)

// Ledger (gfx950): launch_bounds 2nd arg acts as min-BLOCKS/CU:
//   (512,4)->64-reg cap (spill, 640us); (512,1)/bare-> heuristic picks 128
//   + spills a 128-float tile (r7/r8, ~350us). Fix: amdgpu_waves_per_eu(2,2)
//   pins occupancy target to 2 waves/EU -> 256-reg budget, no incentive to
//   shrink. 256-thr blocks (4 waves): 8 waves/CU = 2 blocks/CU -> all 512
//   blocks co-resident. Host gates: localSizeBytes==0 (no spill) AND
//   occupancy>=2, else known-good fallback. Partials live in d_out (dead
//   until final store) so no ws_size dependence.
__global__ __launch_bounds__(NTHR)
__attribute__((amdgpu_waves_per_eu(2, 2)))
void k_fused(
    const float* __restrict__ x, const float* __restrict__ w4,
    const float* __restrict__ b4, float* __restrict__ out,
    float* __restrict__ ws)
{
    cg::grid_group grid = cg::this_grid();
    const int t    = threadIdx.x;
    const int blk  = blockIdx.x;
    const int lane = t & 63;
    const int wv   = t >> 6;
    const int row0 = blk * RPB;
    const int c0   = t * CPT;

    float* pscr  = out;          // [NBLK][2][DD] scratch in d_out (8.4 MB < 64 MB)
    float* mu_g  = ws;           // [DD]
    float* inv_g = ws + DD;      // [DD]

    __shared__ float lds_red[NWV][RPB];  // 4 x 16
    __shared__ float lds_s[RPB];         // 16
    __shared__ float lds_st[NWV][8];     // 4 x (4 sum + 4 sq)

    // v holds the (normalized) running `out`; starts as x. 128 VGPRs.
    float v[RPB][CPT];
    {
        const float* xp = x + (size_t)row0 * DD + c0;
        #pragma unroll
        for (int r = 0; r < RPB; ++r) {
            *(float4*)&v[r][0] = *(const float4*)xp;
            *(float4*)&v[r][4] = *(const float4*)(xp + 4);
            xp += DD;
        }
    }

    for (int l = 0; l < 4; ++l) {
        // ---- row dot: s[row] = sum_d v[row,d] * w[l,d]  (block-local)
        {
            float wr[CPT];
            *(float4*)&wr[0] = *(const float4*)(w4 + l * DD + c0);
            *(float4*)&wr[4] = *(const float4*)(w4 + l * DD + c0 + 4);
            #pragma unroll
            for (int ch = 0; ch < RPB / 8; ++ch) {
                float p[8];
                #pragma unroll
                for (int i = 0; i < 8; ++i) {
                    const int r = ch * 8 + i;
                    float a = v[r][0] * wr[0];
                    #pragma unroll
                    for (int j = 1; j < CPT; ++j) a = fmaf(v[r][j], wr[j], a);
                    p[i] = a;
                }
                #pragma unroll
                for (int off = 32; off; off >>= 1) {
                    #pragma unroll
                    for (int i = 0; i < 8; ++i)
                        p[i] += __shfl_xor(p[i], off, 64);
                }
                if (lane == 0) {
                    #pragma unroll
                    for (int i = 0; i < 8; ++i) lds_red[wv][ch * 8 + i] = p[i];
                }
            }
        }
        __syncthreads();
        if (t < RPB) {
            float a = 0.f;
            #pragma unroll
            for (int w = 0; w < NWV; ++w) a += lds_red[w][t];
            lds_s[t] = a;
        }
        __syncthreads();

        // ---- update: v = x*s + bias + v
        {
            float bv[CPT];
            *(float4*)&bv[0] = *(const float4*)(b4 + l * DD + c0);
            *(float4*)&bv[4] = *(const float4*)(b4 + l * DD + c0 + 4);
            const float* xp = x + (size_t)row0 * DD + c0;
            #pragma unroll
            for (int r = 0; r < RPB; ++r) {
                float xv[CPT];
                *(float4*)&xv[0] = *(const float4*)xp;
                *(float4*)&xv[4] = *(const float4*)(xp + 4);
                xp += DD;
                const float sv = lds_s[r];
                #pragma unroll
                for (int j = 0; j < CPT; ++j)
                    v[r][j] = fmaf(xv[j], sv, bv[j] + v[r][j]);
            }
        }

        // ---- column partials (register-only post-pass over v)
        {
            float cs[CPT], cq[CPT];
            #pragma unroll
            for (int j = 0; j < CPT; ++j) { cs[j] = 0.f; cq[j] = 0.f; }
            #pragma unroll
            for (int r = 0; r < RPB; ++r) {
                #pragma unroll
                for (int j = 0; j < CPT; ++j) {
                    cs[j] += v[r][j];
                    cq[j]  = fmaf(v[r][j], v[r][j], cq[j]);
                }
            }
            float* pp = pscr + (size_t)blk * 2 * DD;
            *(float4*)(pp + c0)          = *(float4*)&cs[0];
            *(float4*)(pp + c0 + 4)      = *(float4*)&cs[4];
            *(float4*)(pp + DD + c0)     = *(float4*)&cq[0];
            *(float4*)(pp + DD + c0 + 4) = *(float4*)&cq[4];
        }

        grid.sync();

        // ---- stats reduce: block b owns cols [4b, 4b+4)
        // thread t covers partial-sets {t, t+256}; wave butterfly; cross-wave LDS.
        {
            const int cb = blk * 4;
            const float* p0 = pscr + (size_t)t * 2 * DD;
            const float* p1 = pscr + (size_t)(t + 256) * 2 * DD;
            float a[4], q[4];
            {
                const float4 a0 = *(const float4*)(p0 + cb);
                const float4 a1 = *(const float4*)(p1 + cb);
                const float4 q0 = *(const float4*)(p0 + DD + cb);
                const float4 q1 = *(const float4*)(p1 + DD + cb);
                a[0] = a0.x + a1.x; a[1] = a0.y + a1.y;
                a[2] = a0.z + a1.z; a[3] = a0.w + a1.w;
                q[0] = q0.x + q1.x; q[1] = q0.y + q1.y;
                q[2] = q0.z + q1.z; q[3] = q0.w + q1.w;
            }
            #pragma unroll
            for (int off = 32; off; off >>= 1) {
                #pragma unroll
                for (int j = 0; j < 4; ++j) {
                    a[j] += __shfl_xor(a[j], off, 64);
                    q[j] += __shfl_xor(q[j], off, 64);
                }
            }
            if (lane == 0) {
                #pragma unroll
                for (int j = 0; j < 4; ++j) {
                    lds_st[wv][j]     = a[j];
                    lds_st[wv][4 + j] = q[j];
                }
            }
            __syncthreads();
            if (t == 0) {
                #pragma unroll
                for (int j = 0; j < 4; ++j) {
                    float A = lds_st[0][j] + lds_st[1][j] + lds_st[2][j] + lds_st[3][j];
                    float Q = lds_st[0][4 + j] + lds_st[1][4 + j] + lds_st[2][4 + j] + lds_st[3][4 + j];
                    const float m  = A / (float)BB;
                    const float va = fmaxf(Q / (float)BB - m * m, 0.f);
                    mu_g[cb + j]  = m;
                    inv_g[cb + j] = rsqrtf(va + BN_EPS);
                }
            }
        }

        grid.sync();

        // ---- normalize registers
        {
            float mv[CPT], iv[CPT];
            *(float4*)&mv[0] = *(const float4*)(mu_g + c0);
            *(float4*)&mv[4] = *(const float4*)(mu_g + c0 + 4);
            *(float4*)&iv[0] = *(const float4*)(inv_g + c0);
            *(float4*)&iv[4] = *(const float4*)(inv_g + c0 + 4);
            #pragma unroll
            for (int r = 0; r < RPB; ++r) {
                #pragma unroll
                for (int j = 0; j < CPT; ++j)
                    v[r][j] = (v[r][j] - mv[j]) * iv[j];
            }
        }
    }

    // ---- final store (overwrites the pscr scratch region too)
    {
        float* op = out + (size_t)row0 * DD + c0;
        #pragma unroll
        for (int r = 0; r < RPB; ++r) {
            *(float4*)op       = *(float4*)&v[r][0];
            *(float4*)(op + 4) = *(float4*)&v[r][4];
            op += DD;
        }
    }
}

// ---------------- fallback: merged per-layer kernel (r9 known-good, 281us) ----
__global__ __launch_bounds__(512) void k_layer(
    const float* __restrict__ x, const float* __restrict__ raw,
    const float* __restrict__ w, const float* __restrict__ bias,
    const float* __restrict__ mu, const float* __restrict__ inv,
    float* __restrict__ outbuf, float* __restrict__ partials, int use_norm)
{
    const int t    = threadIdx.x;
    const int lane = t & 63;
    const int wv   = t >> 6;
    const int blk  = blockIdx.x;
    const int row0 = blk * 32;

    __shared__ float lds_s[32];

    for (int rw = 0; rw < 4; ++rw) {
        const int row = row0 + wv * 4 + rw;
        const float* rp = raw + (size_t)row * DD;
        float acc = 0.f;
        #pragma unroll
        for (int k = 0; k < DD / 256; ++k) {
            const int idx = k * 256 + lane * 4;
            float4 rv  = *(const float4*)(rp + idx);
            const float4 wv4 = *(const float4*)(w + idx);
            if (use_norm) {
                const float4 m  = *(const float4*)(mu + idx);
                const float4 iv = *(const float4*)(inv + idx);
                rv.x = (rv.x - m.x) * iv.x;
                rv.y = (rv.y - m.y) * iv.y;
                rv.z = (rv.z - m.z) * iv.z;
                rv.w = (rv.w - m.w) * iv.w;
            }
            acc += rv.x * wv4.x + rv.y * wv4.y + rv.z * wv4.z + rv.w * wv4.w;
        }
        #pragma unroll
        for (int off = 32; off; off >>= 1) acc += __shfl_xor(acc, off, 64);
        if (lane == 0) lds_s[wv * 4 + rw] = acc;
    }
    __syncthreads();

    const int c0 = t * 4;
    float4 bv = *(const float4*)(bias + c0);
    float4 m4, iv4;
    if (use_norm) {
        m4  = *(const float4*)(mu + c0);
        iv4 = *(const float4*)(inv + c0);
    } else {
        m4  = make_float4(0.f, 0.f, 0.f, 0.f);
        iv4 = make_float4(1.f, 1.f, 1.f, 1.f);
    }
    float cs[4] = {0.f, 0.f, 0.f, 0.f};
    float cq[4] = {0.f, 0.f, 0.f, 0.f};
    const float* rp = raw + (size_t)row0 * DD + c0;
    const float* xp = x   + (size_t)row0 * DD + c0;
    float*       op = outbuf + (size_t)row0 * DD + c0;
    for (int r = 0; r < 32; ++r) {
        const float4 rv = *(const float4*)rp;
        const float4 x4 = *(const float4*)xp;
        const float  sv = lds_s[r];
        float4 o;
        o.x = fmaf(x4.x, sv, bv.x + (rv.x - m4.x) * iv4.x);
        o.y = fmaf(x4.y, sv, bv.y + (rv.y - m4.y) * iv4.y);
        o.z = fmaf(x4.z, sv, bv.z + (rv.z - m4.z) * iv4.z);
        o.w = fmaf(x4.w, sv, bv.w + (rv.w - m4.w) * iv4.w);
        cs[0] += o.x; cq[0] = fmaf(o.x, o.x, cq[0]);
        cs[1] += o.y; cq[1] = fmaf(o.y, o.y, cq[1]);
        cs[2] += o.z; cq[2] = fmaf(o.z, o.z, cq[2]);
        cs[3] += o.w; cq[3] = fmaf(o.w, o.w, cq[3]);
        *(float4*)op = o;
        rp += DD; xp += DD; op += DD;
    }
    float* pp = partials + (size_t)blk * 2 * DD;
    *(float4*)(pp + c0)      = *(float4*)&cs[0];
    *(float4*)(pp + DD + c0) = *(float4*)&cq[0];
}

__global__ __launch_bounds__(256) void k_stats(
    const float* __restrict__ partials, float* __restrict__ mu, float* __restrict__ inv)
{
    const int col = blockIdx.x * 256 + threadIdx.x;  // grid = DD/256 = 8
    float sum = 0.f, sq = 0.f;
    for (int p = 0; p < 256; ++p) {
        sum += partials[(size_t)p * 2 * DD + col];
        sq  += partials[(size_t)p * 2 * DD + DD + col];
    }
    const float m = sum / (float)BB;
    const float var = fmaxf(sq / (float)BB - m * m, 0.f);
    mu[col]  = m;
    inv[col] = rsqrtf(var + BN_EPS);
}

__global__ __launch_bounds__(256) void k_norm(
    float* __restrict__ out, const float* __restrict__ mu, const float* __restrict__ inv)
{
    const size_t i = ((size_t)blockIdx.x * 256 + threadIdx.x) * 4;
    const int c = (int)(i & (DD - 1));
    float4 v = *(float4*)(out + i);
    const float4 m  = *(const float4*)(mu + c);
    const float4 iv = *(const float4*)(inv + c);
    v.x = (v.x - m.x) * iv.x;
    v.y = (v.y - m.y) * iv.y;
    v.z = (v.z - m.z) * iv.z;
    v.w = (v.w - m.w) * iv.w;
    *(float4*)(out + i) = v;
}

extern "C" void kernel_launch(void* const* d_in, const int* in_sizes, int n_in,
                              void* d_out, int out_size, void* d_ws, size_t ws_size,
                              hipStream_t stream) {
    const float* x  = (const float*)d_in[0];   // [B, D]
    const float* w  = (const float*)d_in[1];   // [4, D]
    const float* bb = (const float*)d_in[2];   // [4, D]
    float* out = (float*)d_out;
    float* ws  = (float*)d_ws;

    // ---- coop path: require (a) no spill (localSizeBytes==0), (b) >=2
    // blocks/CU so all 512 blocks are co-resident (ROCm does NOT validate
    // co-residency; oversubscription deadlocks grid.sync). ws only needs
    // mu/inv (16 KB): partials live inside d_out.
    bool coop_ok = false;
    if (ws_size >= 2 * DD * sizeof(float)) {
        hipFuncAttributes fa;
        hipError_t ae = hipFuncGetAttributes(&fa, (const void*)k_fused);
        int blocks_per_cu = 0;
        hipError_t qe = hipOccupancyMaxActiveBlocksPerMultiprocessor(
            &blocks_per_cu, (const void*)k_fused, NTHR, 0);
        if (ae == hipSuccess && qe == hipSuccess &&
            fa.localSizeBytes == 0 && blocks_per_cu >= 2) {
            void* args[] = { (void*)&x, (void*)&w, (void*)&bb, (void*)&out, (void*)&ws };
            hipError_t e = hipLaunchCooperativeKernel((const void*)k_fused, dim3(NBLK),
                                                      dim3(NTHR), args, 0, stream);
            coop_ok = (e == hipSuccess);
        }
    }
    if (coop_ok) return;

    // ---- fallback: merged per-layer path (9 dispatches, known-good ~281us)
    float* mu_buf   = ws;
    float* inv_buf  = mu_buf + DD;
    float* partials = inv_buf + DD;   // [256][2][DD] = 4 MB

    for (int l = 0; l < 4; ++l) {
        const float* raw = (l == 0) ? x : out;
        k_layer<<<256, 512, 0, stream>>>(x, raw, w + l * DD, bb + l * DD,
                                         mu_buf, inv_buf, out, partials, l != 0);
        k_stats<<<DD / 256, 256, 0, stream>>>(partials, mu_buf, inv_buf);
    }
    k_norm<<<(BB * DD / 4) / 256, 256, 0, stream>>>(out, mu_buf, inv_buf);
}

// Round 11
// 274.141 us; speedup vs baseline: 1.1881x; 1.1881x over previous
//
#include <hip/hip_runtime.h>
#include <hip/hip_cooperative_groups.h>
#include <math.h>

namespace cg = cooperative_groups;

#define BB 8192
#define DD 2048
#define BN_EPS 1e-5f

// ---------------- cooperative fused path (fits the 128-VGPR budget) ----------
#define NBLK 1024
#define NTHR 256
#define RPB  8    // rows per block   (NBLK * RPB == BB)
#define CPT  8    // cols per thread  (NTHR * CPT == DD)
#define NWV  (NTHR / 64)

// Six-round ledger: compiler refuses >128-VGPR spill-free allocations for
// this family; any per-thread state of 128 floats spills (r4/r7/r8/r10).
// So design INTO 128: v[8][8]=64 floats state, ~105 total regs.
// (256,4): 2nd arg acts as min-BLOCKS/CU -> 16 waves/CU -> 128-reg cap,
// and 4 blocks/CU is exactly the co-residency 1024 blocks need.
// Host gates: localSizeBytes==0 (no spill) AND occupancy>=4, else fallback
// (ROCm coop launch does NOT validate co-residency; oversubscription
// deadlocks grid.sync - r5). Partials live in d_out scratch (16MB < 64MB).
__global__ __launch_bounds__(NTHR, 4) void k_fused(
    const float* __restrict__ x, const float* __restrict__ w4,
    const float* __restrict__ b4, float* __restrict__ out,
    float* __restrict__ ws)
{
    cg::grid_group grid = cg::this_grid();
    const int t    = threadIdx.x;
    const int blk  = blockIdx.x;
    const int lane = t & 63;
    const int wv   = t >> 6;
    const int row0 = blk * RPB;
    const int c0   = t * CPT;

    float* pscr  = out;          // [NBLK][2][DD] scratch inside d_out (16 MB)
    float* mu_g  = ws;           // [DD]
    float* inv_g = ws + DD;      // [DD]

    __shared__ float lds_red[NWV][RPB];
    __shared__ float lds_s[RPB];
    __shared__ float lds_st[NWV][4];

    // v = running (normalized) out; starts as x.  64 VGPRs of state.
    float v[RPB][CPT];
    {
        const float* xp = x + (size_t)row0 * DD + c0;
        #pragma unroll
        for (int r = 0; r < RPB; ++r) {
            *(float4*)&v[r][0] = *(const float4*)xp;
            *(float4*)&v[r][4] = *(const float4*)(xp + 4);
            xp += DD;
        }
    }

    for (int l = 0; l < 4; ++l) {
        // ---- row dot (block-local)
        {
            float wr[CPT];
            *(float4*)&wr[0] = *(const float4*)(w4 + l * DD + c0);
            *(float4*)&wr[4] = *(const float4*)(w4 + l * DD + c0 + 4);
            float p[RPB];
            #pragma unroll
            for (int r = 0; r < RPB; ++r) {
                float a = v[r][0] * wr[0];
                #pragma unroll
                for (int j = 1; j < CPT; ++j) a = fmaf(v[r][j], wr[j], a);
                p[r] = a;
            }
            #pragma unroll
            for (int off = 32; off; off >>= 1) {
                #pragma unroll
                for (int r = 0; r < RPB; ++r)
                    p[r] += __shfl_xor(p[r], off, 64);
            }
            if (lane == 0) {
                #pragma unroll
                for (int r = 0; r < RPB; ++r) lds_red[wv][r] = p[r];
            }
        }
        __syncthreads();
        if (t < RPB) {
            float a = 0.f;
            #pragma unroll
            for (int w = 0; w < NWV; ++w) a += lds_red[w][t];
            lds_s[t] = a;
        }
        __syncthreads();

        // ---- update v = x*s + bias + v
        {
            float bv[CPT];
            *(float4*)&bv[0] = *(const float4*)(b4 + l * DD + c0);
            *(float4*)&bv[4] = *(const float4*)(b4 + l * DD + c0 + 4);
            const float* xp = x + (size_t)row0 * DD + c0;
            #pragma unroll
            for (int r = 0; r < RPB; ++r) {
                float xv[CPT];
                *(float4*)&xv[0] = *(const float4*)xp;
                *(float4*)&xv[4] = *(const float4*)(xp + 4);
                xp += DD;
                const float sv = lds_s[r];
                #pragma unroll
                for (int j = 0; j < CPT; ++j)
                    v[r][j] = fmaf(xv[j], sv, bv[j] + v[r][j]);
            }
        }

        // ---- column partials
        {
            float cs[CPT], cq[CPT];
            #pragma unroll
            for (int j = 0; j < CPT; ++j) { cs[j] = 0.f; cq[j] = 0.f; }
            #pragma unroll
            for (int r = 0; r < RPB; ++r) {
                #pragma unroll
                for (int j = 0; j < CPT; ++j) {
                    cs[j] += v[r][j];
                    cq[j]  = fmaf(v[r][j], v[r][j], cq[j]);
                }
            }
            float* pp = pscr + (size_t)blk * 2 * DD;
            *(float4*)(pp + c0)          = *(float4*)&cs[0];
            *(float4*)(pp + c0 + 4)      = *(float4*)&cs[4];
            *(float4*)(pp + DD + c0)     = *(float4*)&cq[0];
            *(float4*)(pp + DD + c0 + 4) = *(float4*)&cq[4];
        }

        grid.sync();

        // ---- stats reduce: block b owns cols {2b, 2b+1}
        {
            const int cb = blk * 2;
            float a0 = 0.f, a1 = 0.f, q0 = 0.f, q1 = 0.f;
            #pragma unroll
            for (int k = 0; k < NBLK / NTHR; ++k) {
                const float* pb = pscr + (size_t)(t + k * NTHR) * 2 * DD;
                a0 += pb[cb];      a1 += pb[cb + 1];
                q0 += pb[DD + cb]; q1 += pb[DD + cb + 1];
            }
            #pragma unroll
            for (int off = 32; off; off >>= 1) {
                a0 += __shfl_xor(a0, off, 64);
                a1 += __shfl_xor(a1, off, 64);
                q0 += __shfl_xor(q0, off, 64);
                q1 += __shfl_xor(q1, off, 64);
            }
            if (lane == 0) {
                lds_st[wv][0] = a0; lds_st[wv][1] = q0;
                lds_st[wv][2] = a1; lds_st[wv][3] = q1;
            }
            __syncthreads();
            if (t == 0) {
                float A0 = lds_st[0][0] + lds_st[1][0] + lds_st[2][0] + lds_st[3][0];
                float Q0 = lds_st[0][1] + lds_st[1][1] + lds_st[2][1] + lds_st[3][1];
                float A1 = lds_st[0][2] + lds_st[1][2] + lds_st[2][2] + lds_st[3][2];
                float Q1 = lds_st[0][3] + lds_st[1][3] + lds_st[2][3] + lds_st[3][3];
                const float m0 = A0 / (float)BB, m1 = A1 / (float)BB;
                mu_g[cb]      = m0;
                mu_g[cb + 1]  = m1;
                inv_g[cb]     = rsqrtf(fmaxf(Q0 / (float)BB - m0 * m0, 0.f) + BN_EPS);
                inv_g[cb + 1] = rsqrtf(fmaxf(Q1 / (float)BB - m1 * m1, 0.f) + BN_EPS);
            }
        }

        grid.sync();

        // ---- normalize registers
        {
            float mv[CPT], iv[CPT];
            *(float4*)&mv[0] = *(const float4*)(mu_g + c0);
            *(float4*)&mv[4] = *(const float4*)(mu_g + c0 + 4);
            *(float4*)&iv[0] = *(const float4*)(inv_g + c0);
            *(float4*)&iv[4] = *(const float4*)(inv_g + c0 + 4);
            #pragma unroll
            for (int r = 0; r < RPB; ++r) {
                #pragma unroll
                for (int j = 0; j < CPT; ++j)
                    v[r][j] = (v[r][j] - mv[j]) * iv[j];
            }
        }
    }

    // ---- final store (overwrites pscr scratch)
    {
        float* op = out + (size_t)row0 * DD + c0;
        #pragma unroll
        for (int r = 0; r < RPB; ++r) {
            *(float4*)op       = *(float4*)&v[r][0];
            *(float4*)(op + 4) = *(float4*)&v[r][4];
            op += DD;
        }
    }
}

// ---------------- optimized fallback: high-occupancy per-layer kernel --------
// rows per block is runtime (8/16/32 depending on ws budget). 256-thr blocks:
// at 8 rows -> 1024 blocks -> 4 blocks/CU @ ~56 VGPR -> 16 waves/CU (vs r10's
// 8), and the phase-2 raw re-read stays L2-resident (64KB/block).
__global__ __launch_bounds__(256) void k_layer2(
    const float* __restrict__ x, const float* __restrict__ raw,
    const float* __restrict__ w, const float* __restrict__ bias,
    const float* __restrict__ mu, const float* __restrict__ inv,
    float* __restrict__ outbuf, float* __restrict__ partials,
    int rows, int use_norm)
{
    const int t    = threadIdx.x;
    const int lane = t & 63;
    const int wv   = t >> 6;
    const int blk  = blockIdx.x;
    const int row0 = blk * rows;

    __shared__ float lds_s[32];

    // phase 1: dots; wave wv handles rows wv, wv+4, ...
    for (int rr = wv; rr < rows; rr += 4) {
        const float* rp = raw + (size_t)(row0 + rr) * DD;
        float acc = 0.f;
        #pragma unroll
        for (int k = 0; k < DD / 256; ++k) {
            const int idx = k * 256 + lane * 4;
            float4 rv  = *(const float4*)(rp + idx);
            const float4 wv4 = *(const float4*)(w + idx);
            if (use_norm) {
                const float4 m  = *(const float4*)(mu + idx);
                const float4 iv = *(const float4*)(inv + idx);
                rv.x = (rv.x - m.x) * iv.x;
                rv.y = (rv.y - m.y) * iv.y;
                rv.z = (rv.z - m.z) * iv.z;
                rv.w = (rv.w - m.w) * iv.w;
            }
            acc += rv.x * wv4.x + rv.y * wv4.y + rv.z * wv4.z + rv.w * wv4.w;
        }
        #pragma unroll
        for (int off = 32; off; off >>= 1) acc += __shfl_xor(acc, off, 64);
        if (lane == 0) lds_s[rr] = acc;
    }
    __syncthreads();

    // phase 2: update rows at this thread's 8 columns
    const int c0 = t * 8;
    float bv[8], mv[8], iv8[8];
    *(float4*)&bv[0] = *(const float4*)(bias + c0);
    *(float4*)&bv[4] = *(const float4*)(bias + c0 + 4);
    if (use_norm) {
        *(float4*)&mv[0]  = *(const float4*)(mu + c0);
        *(float4*)&mv[4]  = *(const float4*)(mu + c0 + 4);
        *(float4*)&iv8[0] = *(const float4*)(inv + c0);
        *(float4*)&iv8[4] = *(const float4*)(inv + c0 + 4);
    } else {
        #pragma unroll
        for (int j = 0; j < 8; ++j) { mv[j] = 0.f; iv8[j] = 1.f; }
    }
    float cs[8], cq[8];
    #pragma unroll
    for (int j = 0; j < 8; ++j) { cs[j] = 0.f; cq[j] = 0.f; }

    const float* rp = raw + (size_t)row0 * DD + c0;
    const float* xp = x   + (size_t)row0 * DD + c0;
    float*       op = outbuf + (size_t)row0 * DD + c0;
    for (int r = 0; r < rows; ++r) {
        float rv[8], xv[8];
        *(float4*)&rv[0] = *(const float4*)rp;
        *(float4*)&rv[4] = *(const float4*)(rp + 4);
        *(float4*)&xv[0] = *(const float4*)xp;
        *(float4*)&xv[4] = *(const float4*)(xp + 4);
        const float sv = lds_s[r];
        float o[8];
        #pragma unroll
        for (int j = 0; j < 8; ++j) {
            o[j] = fmaf(xv[j], sv, bv[j] + (rv[j] - mv[j]) * iv8[j]);
            cs[j] += o[j];
            cq[j]  = fmaf(o[j], o[j], cq[j]);
        }
        *(float4*)op       = *(float4*)&o[0];
        *(float4*)(op + 4) = *(float4*)&o[4];
        rp += DD; xp += DD; op += DD;
    }
    float* pp = partials + (size_t)blk * 2 * DD;
    *(float4*)(pp + c0)          = *(float4*)&cs[0];
    *(float4*)(pp + c0 + 4)      = *(float4*)&cs[4];
    *(float4*)(pp + DD + c0)     = *(float4*)&cq[0];
    *(float4*)(pp + DD + c0 + 4) = *(float4*)&cq[4];
}

// Stage A: [nb][2*DD] -> [16][2*DD]
__global__ __launch_bounds__(256) void k_stats_a(
    const float* __restrict__ partials, float* __restrict__ mid, int nb_per_pg)
{
    const int pg = blockIdx.x >> 4;       // 16 groups
    const int ec = blockIdx.x & 15;       // 16 chunks of 256 over 2*DD=4096
    const int e  = ec * 256 + threadIdx.x;
    const int p0 = pg * nb_per_pg;
    float acc = 0.f;
    for (int p = 0; p < nb_per_pg; ++p)
        acc += partials[(size_t)(p0 + p) * (2 * DD) + e];
    mid[(size_t)pg * (2 * DD) + e] = acc;
}

// Stage B: [16][2*DD] -> mu, inv
__global__ __launch_bounds__(256) void k_stats_b(
    const float* __restrict__ mid, float* __restrict__ mu, float* __restrict__ inv)
{
    const int col = blockIdx.x * 256 + threadIdx.x;   // grid = DD/256 = 8
    float sum = 0.f, sq = 0.f;
    #pragma unroll
    for (int p = 0; p < 16; ++p) {
        sum += mid[(size_t)p * 2 * DD + col];
        sq  += mid[(size_t)p * 2 * DD + DD + col];
    }
    const float m = sum / (float)BB;
    const float var = fmaxf(sq / (float)BB - m * m, 0.f);
    mu[col]  = m;
    inv[col] = rsqrtf(var + BN_EPS);
}

__global__ __launch_bounds__(256) void k_norm(
    float* __restrict__ out, const float* __restrict__ mu, const float* __restrict__ inv)
{
    const size_t i = ((size_t)blockIdx.x * 256 + threadIdx.x) * 4;
    const int c = (int)(i & (DD - 1));
    float4 v = *(float4*)(out + i);
    const float4 m  = *(const float4*)(mu + c);
    const float4 iv = *(const float4*)(inv + c);
    v.x = (v.x - m.x) * iv.x;
    v.y = (v.y - m.y) * iv.y;
    v.z = (v.z - m.z) * iv.z;
    v.w = (v.w - m.w) * iv.w;
    *(float4*)(out + i) = v;
}

extern "C" void kernel_launch(void* const* d_in, const int* in_sizes, int n_in,
                              void* d_out, int out_size, void* d_ws, size_t ws_size,
                              hipStream_t stream) {
    const float* x  = (const float*)d_in[0];   // [B, D]
    const float* w  = (const float*)d_in[1];   // [4, D]
    const float* bb = (const float*)d_in[2];   // [4, D]
    float* out = (float*)d_out;
    float* ws  = (float*)d_ws;

    // ---- coop path: gates = no spill + >=4 blocks/CU (1024 blocks / 256 CUs)
    bool coop_ok = false;
    if (ws_size >= 2 * DD * sizeof(float)) {
        hipFuncAttributes fa;
        hipError_t ae = hipFuncGetAttributes(&fa, (const void*)k_fused);
        int blocks_per_cu = 0;
        hipError_t qe = hipOccupancyMaxActiveBlocksPerMultiprocessor(
            &blocks_per_cu, (const void*)k_fused, NTHR, 0);
        if (ae == hipSuccess && qe == hipSuccess &&
            fa.localSizeBytes == 0 && blocks_per_cu >= 4) {
            void* args[] = { (void*)&x, (void*)&w, (void*)&bb, (void*)&out, (void*)&ws };
            hipError_t e = hipLaunchCooperativeKernel((const void*)k_fused, dim3(NBLK),
                                                      dim3(NTHR), args, 0, stream);
            coop_ok = (e == hipSuccess);
        }
    }
    if (coop_ok) return;

    // ---- fallback: optimized multi-kernel path
    // ws layout (floats): mu[DD] | inv[DD] | mid[16*2*DD] | partials[nb*2*DD]
    float* mu_buf   = ws;
    float* inv_buf  = mu_buf + DD;
    float* mid_buf  = inv_buf + DD;
    float* partials = mid_buf + 16 * 2 * DD;
    const size_t base_bytes = (size_t)(partials - ws) * sizeof(float);

    int nb = 1024;
    while (nb > 256 && base_bytes + (size_t)nb * 2 * DD * sizeof(float) > ws_size)
        nb >>= 1;
    const int rows = BB / nb;

    for (int l = 0; l < 4; ++l) {
        const float* raw = (l == 0) ? x : out;
        k_layer2<<<nb, 256, 0, stream>>>(x, raw, w + l * DD, bb + l * DD,
                                         mu_buf, inv_buf, out, partials, rows, l != 0);
        k_stats_a<<<256, 256, 0, stream>>>(partials, mid_buf, nb / 16);
        k_stats_b<<<DD / 256, 256, 0, stream>>>(mid_buf, mu_buf, inv_buf);
    }
    k_norm<<<(BB * DD / 4) / 256, 256, 0, stream>>>(out, mu_buf, inv_buf);
}